// Round 9
// baseline (541.806 us; speedup 1.0000x reference)
//
#include <hip/hip_runtime.h>
#include <hip/hip_cooperative_groups.h>

namespace cg = cooperative_groups;

#define BB 8
#define NN 512
#define PP 32

// ws layout (float offsets)
#define OFF_BASE1 0
#define OFF_BASE2 131072
#define OFF_T21   262144
#define OFF_T22   393216
#define OFF_PART  524288   // [nq8][b8][jt8][p32][j64] = 1,048,576 floats

struct SmemA {                      // phase A: 19.4 KB
    float4 t4lds[3][32];            // 1.5 KB
    float  part[4][16][68];         // 17.4 KB (per-wave, half of p at a time)
    float  cbuf[4][32];             // 0.5 KB
};
struct SmemL {                      // layer phases: 16.6 KB
    float tlds[64*32];              // tmp2 slab [n64][p32]
    float muT[32][66];              // mu exchange, padded
};
union SmemU { SmemA a; SmemL l; };

// ---------------------------------------------------------------------------
// Phase A unit (one wave, one (l,b,n)):
//   t31[p][n] = sum_m relu(t4[p,1]*w[n,m] + (-0.5 t4[p,2] s_n)*s_m
//                          + (t4[p,0]x_n + 0.5 t4[p,2] + t4[p,3]))
//   base_l[n][p] = t1-term + sum_q t3[p][q] t31[q][n]
//   l==0: tmp2_1[n][p] = sum_q t2[1][p][q] relu(base0[q][n])
// p handled in two 16-halves; per-half: 16 LDS rows + quad shfl_xor reduce.
// All LDS traffic is wave-local (in-order per wave, no __syncthreads).
// ---------------------------------------------------------------------------
__device__ __forceinline__ void phaseA_unit(
    int u, const float* __restrict__ x, const float* __restrict__ wts,
    const float* __restrict__ extra, const float* __restrict__ t1,
    const float* __restrict__ t2, const float* __restrict__ t3,
    float* __restrict__ ws, SmemA& sm, int wv, int lane)
{
    const int l = u >> 12;            // 4096 units per layer
    const int b = (u >> 9) & 7;
    const int n = u & 511;

    const float* xrow = x + b*NN;
    const float* wrow = wts + ((size_t)b*NN + n)*NN;
    const float4 wa = *(const float4*)(wrow + lane*4);
    const float4 wb = *(const float4*)(wrow + 256 + lane*4);
    const float4 xa = *(const float4*)(xrow + lane*4);
    const float4 xb = *(const float4*)(xrow + 256 + lane*4);
    const float4 sva = { 2.f*xa.x-1.f, 2.f*xa.y-1.f, 2.f*xa.z-1.f, 2.f*xa.w-1.f };
    const float4 svb = { 2.f*xb.x-1.f, 2.f*xb.y-1.f, 2.f*xb.z-1.f, 2.f*xb.w-1.f };
    const float xn = xrow[n];
    const float en = extra[b*NN + n];
    const float sn = 2.f*xn - 1.f;

    const int ph = lane >> 2;         // p-row this lane helps reduce (0..15)
    const int qt = lane & 3;          // quarter of the 64 m-columns

#pragma unroll
    for (int hf = 0; hf < 2; ++hf) {
#pragma unroll
        for (int pp = 0; pp < 16; ++pp) {
            const float4 c4 = sm.t4lds[l][hf*16 + pp];    // LDS broadcast
            const float Ay = c4.y;
            const float Cc = fmaf(c4.x, xn, fmaf(0.5f, c4.z, c4.w));
            const float Bc = -0.5f*c4.z*sn;
            float a0, a1;
            a0  = fmaxf(0.f, fmaf(Ay, wa.x, fmaf(Bc, sva.x, Cc)));
            a1  = fmaxf(0.f, fmaf(Ay, wa.y, fmaf(Bc, sva.y, Cc)));
            a0 += fmaxf(0.f, fmaf(Ay, wa.z, fmaf(Bc, sva.z, Cc)));
            a1 += fmaxf(0.f, fmaf(Ay, wa.w, fmaf(Bc, sva.w, Cc)));
            a0 += fmaxf(0.f, fmaf(Ay, wb.x, fmaf(Bc, svb.x, Cc)));
            a1 += fmaxf(0.f, fmaf(Ay, wb.y, fmaf(Bc, svb.y, Cc)));
            a0 += fmaxf(0.f, fmaf(Ay, wb.z, fmaf(Bc, svb.z, Cc)));
            a1 += fmaxf(0.f, fmaf(Ay, wb.w, fmaf(Bc, svb.w, Cc)));
            sm.part[wv][pp][lane] = a0 + a1;
        }
        // lane (ph,qt) sums 16 columns of row ph, quad shfl_xor completes
        float r = 0.f;
#pragma unroll
        for (int q = 0; q < 4; ++q) {
            const float4 v = *(const float4*)&sm.part[wv][ph][qt*16 + q*4];
            r += (v.x + v.y) + (v.z + v.w);
        }
        r += __shfl_xor(r, 1, 64);
        r += __shfl_xor(r, 2, 64);
        if (qt == 0) sm.cbuf[wv][hf*16 + ph] = r;          // t31[p][n]
    }

    const int p2 = lane & 31, h = lane >> 5;
    const float* t3r = t3 + l*(PP*PP) + p2*32;
    float term3 = 0.f;
#pragma unroll
    for (int q = 0; q < 8; ++q) {
        const float4 tv = *(const float4*)(t3r + q*4);
        const float4 cv = *(const float4*)&sm.cbuf[wv][q*4];
        term3 = fmaf(tv.x,cv.x, fmaf(tv.y,cv.y, fmaf(tv.z,cv.z, fmaf(tv.w,cv.w, term3))));
    }
    const float* t1r = t1 + l*(PP*3) + p2*3;
    const float term1 = fmaf(t1r[0], 1.f-xn, fmaf(t1r[2], en, t1r[1]));
    const float basev = term1 + term3;

    if (l == 0) {
        const float mu0 = fmaxf(basev, 0.f);
        sm.cbuf[wv][p2] = mu0;
        const float* t2r = t2 + PP*PP + p2*32;             // layer-1 t2
        float s0 = 0.f;
#pragma unroll
        for (int q = 0; q < 8; ++q) {
            const float4 tv = *(const float4*)(t2r + q*4);
            const float4 cv = *(const float4*)&sm.cbuf[wv][q*4];
            s0 = fmaf(tv.x,cv.x, fmaf(tv.y,cv.y, fmaf(tv.z,cv.z, fmaf(tv.w,cv.w, s0))));
        }
        if (h == 0) ws[OFF_T21 + ((size_t)(b*NN + n))*PP + p2] = s0;
    } else {
        float* dst = ws + (l == 1 ? OFF_BASE1 : OFF_BASE2);
        if (h == 0) dst[((size_t)(b*NN + n))*PP + p2] = basev;
    }
}

// ---------------------------------------------------------------------------
// partial: task (b, jt, nq): stage tmp2[b][nq*64..+64][32] in LDS; wave w owns
// p-octet, lane = j. adj reads coalesced (each element fetched once).
// ---------------------------------------------------------------------------
__device__ __forceinline__ void partial_body(
    const float* __restrict__ adj, const float* __restrict__ tmp2in,
    float* __restrict__ partout, SmemL& sm, int tid, int b, int jt, int nq)
{
    const int w    = tid >> 6;   // p-octet 0..3
    const int lane = tid & 63;   // j

    const float4* src = (const float4*)(tmp2in + ((size_t)b*NN + nq*64)*PP);
    ((float4*)sm.tlds)[tid]       = src[tid];
    ((float4*)sm.tlds)[256 + tid] = src[256 + tid];
    __syncthreads();

    float acc[8] = {0.f,0.f,0.f,0.f,0.f,0.f,0.f,0.f};
    const float* adjp = adj + ((size_t)b*NN + nq*64)*NN + jt*64 + lane;
    const float* trow = sm.tlds + w*8;
#pragma unroll 8
    for (int i = 0; i < 64; ++i) {
        const float av = adjp[(size_t)i*NN];               // coalesced
        const float4 ta = *(const float4*)(trow + i*32);       // broadcast
        const float4 tb = *(const float4*)(trow + i*32 + 4);   // broadcast
        acc[0] = fmaf(ta.x, av, acc[0]);
        acc[1] = fmaf(ta.y, av, acc[1]);
        acc[2] = fmaf(ta.z, av, acc[2]);
        acc[3] = fmaf(ta.w, av, acc[3]);
        acc[4] = fmaf(tb.x, av, acc[4]);
        acc[5] = fmaf(tb.y, av, acc[5]);
        acc[6] = fmaf(tb.z, av, acc[6]);
        acc[7] = fmaf(tb.w, av, acc[7]);
    }
    float* pdst = partout + (((size_t)(nq*BB + b)*8 + jt)*PP + w*8)*64 + lane;
#pragma unroll
    for (int t = 0; t < 8; ++t) pdst[t*64] = acc[t];       // coalesced
}

// ---------------------------------------------------------------------------
// reduce: task rblk = (b, jt); 256 thr: j = tid&63, pg = tid>>6 (8 p each).
// ---------------------------------------------------------------------------
__device__ __forceinline__ void reduce_body(
    const float* __restrict__ basein, const float* __restrict__ partin,
    const float* __restrict__ t2l, float* __restrict__ tmp2out,
    float* __restrict__ dout, int final_, SmemL& sm, int tid, int rblk)
{
    const int b  = rblk >> 3;
    const int jt = rblk & 7;
    const int j  = tid & 63;
    const int pg = tid >> 6;          // wave-uniform

    float r[8];
    const float* bp = basein + ((size_t)b*NN + jt*64 + j)*PP + pg*8;
#pragma unroll
    for (int t = 0; t < 8; ++t) r[t] = bp[t];
#pragma unroll
    for (int nq = 0; nq < 8; ++nq) {
        const float* pq = partin
            + ((size_t)((nq*BB + b)*8 + jt)*PP + pg*8)*64 + j;
#pragma unroll
        for (int t = 0; t < 8; ++t) r[t] += pq[t*64];      // coalesced
    }
#pragma unroll
    for (int t = 0; t < 8; ++t) r[t] = fmaxf(r[t], 0.f);

    if (final_) {
#pragma unroll
        for (int t = 0; t < 8; ++t)
            dout[((size_t)b*PP + pg*8 + t)*NN + jt*64 + j] = r[t];
    } else {
#pragma unroll
        for (int t = 0; t < 8; ++t) sm.muT[pg*8 + t][j] = r[t];
        __syncthreads();
        float o[8] = {0.f,0.f,0.f,0.f,0.f,0.f,0.f,0.f};
#pragma unroll
        for (int q = 0; q < 32; ++q) {
            const float mq = sm.muT[q][j];                 // conflict-free
#pragma unroll
            for (int t = 0; t < 8; ++t)
                o[t] = fmaf(t2l[(pg*8 + t)*32 + q], mq, o[t]);  // s_load
        }
        float* od = tmp2out + ((size_t)b*NN + jt*64 + j)*PP + pg*8;
#pragma unroll
        for (int t = 0; t < 8; ++t) od[t] = o[t];
    }
}

// ---------------------------------------------------------------------------
// Fused cooperative kernel: 512 blocks x 256 thr, LDS 19.4KB -> >=2/CU even
// under 64KB LDS accounting (the R6 cooperative-launch failure suspect).
// ---------------------------------------------------------------------------
__global__ __launch_bounds__(256, 2) void k_fused(
    const float* __restrict__ x, const float* __restrict__ adj,
    const float* __restrict__ wts, const float* __restrict__ extra,
    const float* __restrict__ t1, const float* __restrict__ t2,
    const float* __restrict__ t3, const float* __restrict__ t4,
    float* __restrict__ ws, float* __restrict__ out)
{
    cg::grid_group grid = cg::this_grid();
    __shared__ SmemU smu;
    const int tid  = threadIdx.x;
    const int wv   = tid >> 6;
    const int lane = tid & 63;
    const int blk  = blockIdx.x;

    if (tid < 96) smu.a.t4lds[0][tid] = ((const float4*)t4)[tid];
    __syncthreads();
#pragma unroll 1
    for (int k = 0; k < 6; ++k)
        phaseA_unit(k*2048 + blk*4 + wv, x, wts, extra, t1, t2, t3,
                    ws, smu.a, wv, lane);
    __threadfence();
    grid.sync();

    {   const int b = blk >> 6, jt = (blk >> 3) & 7, nq = blk & 7;
        partial_body(adj, ws + OFF_T21, ws + OFF_PART, smu.l, tid, b, jt, nq); }
    __threadfence();
    grid.sync();
    if (blk < 64)
        reduce_body(ws + OFF_BASE1, ws + OFF_PART, t2 + 2*PP*PP,
                    ws + OFF_T22, (float*)nullptr, 0, smu.l, tid, blk);
    __threadfence();
    grid.sync();

    {   const int b = blk >> 6, jt = (blk >> 3) & 7, nq = blk & 7;
        partial_body(adj, ws + OFF_T22, ws + OFF_PART, smu.l, tid, b, jt, nq); }
    __threadfence();
    grid.sync();
    if (blk < 64)
        reduce_body(ws + OFF_BASE2, ws + OFF_PART, (const float*)t2,
                    (float*)nullptr, out, 1, smu.l, tid, blk);
}

// ------------------------- fallback (5 regular launches) -------------------
__global__ __launch_bounds__(256) void k_phaseA(
    const float* __restrict__ x, const float* __restrict__ wts,
    const float* __restrict__ extra, const float* __restrict__ t1,
    const float* __restrict__ t2, const float* __restrict__ t3,
    const float* __restrict__ t4, float* __restrict__ ws)
{
    __shared__ SmemA sma;
    const int tid = threadIdx.x, wv = tid >> 6, lane = tid & 63;
    if (tid < 96) sma.t4lds[0][tid] = ((const float4*)t4)[tid];
    __syncthreads();
    const int wgid = blockIdx.x * 4 + wv;
#pragma unroll 1
    for (int k = 0; k < 3; ++k)
        phaseA_unit(wgid*3 + k, x, wts, extra, t1, t2, t3, ws, sma, wv, lane);
}

__global__ __launch_bounds__(256) void k_partial(
    const float* __restrict__ adj, const float* __restrict__ tmp2in,
    float* __restrict__ partout)
{
    __shared__ SmemL sml;
    const int blk = blockIdx.x;
    partial_body(adj, tmp2in, partout, sml, threadIdx.x,
                 blk >> 6, (blk >> 3) & 7, blk & 7);
}

__global__ __launch_bounds__(256) void k_reduce(
    const float* __restrict__ basein, const float* __restrict__ partin,
    const float* __restrict__ t2l, float* __restrict__ tmp2out,
    float* __restrict__ dout, int final_)
{
    __shared__ SmemL sml;
    reduce_body(basein, partin, t2l, tmp2out, dout, final_, sml,
                threadIdx.x, blockIdx.x);
}

extern "C" void kernel_launch(void* const* d_in, const int* in_sizes, int n_in,
                              void* d_out, int out_size, void* d_ws, size_t ws_size,
                              hipStream_t stream) {
    const float* x     = (const float*)d_in[0];
    const float* adj   = (const float*)d_in[1];
    const float* wts   = (const float*)d_in[2];
    const float* extra = (const float*)d_in[3];
    const float* t1    = (const float*)d_in[4];
    const float* t2    = (const float*)d_in[5];
    const float* t3    = (const float*)d_in[6];
    const float* t4    = (const float*)d_in[7];
    float* out = (float*)d_out;
    float* ws  = (float*)d_ws;

    void* args[] = { (void*)&x, (void*)&adj, (void*)&wts, (void*)&extra,
                     (void*)&t1, (void*)&t2, (void*)&t3, (void*)&t4,
                     (void*)&ws, (void*)&out };
    hipError_t err = hipLaunchCooperativeKernel((void*)k_fused, dim3(512),
                                                dim3(256), args, 0, stream);
    if (err != hipSuccess) {
        (void)hipGetLastError();   // clear sticky error, use fallback path
        hipLaunchKernelGGL(k_phaseA, dim3(1024), dim3(256), 0, stream,
                           x, wts, extra, t1, t2, t3, t4, ws);
        hipLaunchKernelGGL(k_partial, dim3(512), dim3(256), 0, stream,
                           adj, ws + OFF_T21, ws + OFF_PART);
        hipLaunchKernelGGL(k_reduce, dim3(64), dim3(256), 0, stream,
                           ws + OFF_BASE1, ws + OFF_PART, t2 + 2*PP*PP,
                           ws + OFF_T22, (float*)nullptr, 0);
        hipLaunchKernelGGL(k_partial, dim3(512), dim3(256), 0, stream,
                           adj, ws + OFF_T22, ws + OFF_PART);
        hipLaunchKernelGGL(k_reduce, dim3(64), dim3(256), 0, stream,
                           ws + OFF_BASE2, ws + OFF_PART, (const float*)t2,
                           (float*)nullptr, out, 1);
    }
}